// Round 4
// baseline (71.209 us; speedup 1.0000x reference)
//
#include <hip/hip_runtime.h>

// 601-node DAG scan:
//   nodes 0..99 : sigmoid(w_in[i]*x[i] + b_in[i])
//   nodes 100+k : sigmoid(dot4(w_hid[k], vals[edge_idx[k]]) + b_hid[k]),
//                 edge_idx[k][j] < 100+k   (strictly backward edges)
//   output      : vals[600]
//
// Latency-bound (2.6 kFLOP, 18 KB in, 4 B out). One wave, 64 lanes, values
// LDS-resident, sentinel -1.0f = "not ready" (sigmoid outputs are in [0,1]).
//
// Barrier-free ordered sweeps: lane owns nodes k = J*64+lane, slots J=0..7.
// Slots processed in index order; a single wave's LDS ops are program-ordered
// (alias-conservative lgkmcnt + in-order DS pipe), so slot J+1 sees slot J's
// writes with NO s_barrier -> all cross-slot deps resolve in one sweep
// (Gauss-Seidel). Intra-slot chains (rare) resolve in later sweeps; finished
// slots are skipped via wave-uniform __all. Each sweep completes at least the
// lowest-index unfinished node, so the 64-sweep cap is unreachable (expected
// ~3-4 sweeps) — cannot hang, cannot truncate.
//
// Structural floor argument: 501 nodes / 64 lanes = 8 serial gather windows
// minimum; window ≈ 190 cy (4 pipelined ds_read + dot4+exp+rcp). Compute
// ≈ 0.85 µs; graph-replay launch overhead (~2-5 µs) dominates.
//
// Params prefetched into NAMED registers (runtime-indexed register arrays
// spill to scratch) so all ~24 cold vmem loads share one latency window,
// overlapped with input-node compute.

#define NUM_IN  100
#define NUM_HID 501
#define TOTAL   601

__launch_bounds__(64, 1)
__global__ void dag_kernel(const float* __restrict__ x,
                           const float* __restrict__ w_in,
                           const float* __restrict__ b_in,
                           const float* __restrict__ w_hid,
                           const float* __restrict__ b_hid,
                           const int*   __restrict__ edge_idx,
                           float* __restrict__ out) {
    __shared__ float vals[TOTAL];
    const int lane = threadIdx.x;  // 0..63, single wave

    // ---- prefetch per-owned-node params (8 nodes/lane, strided) ----
#define LOADP(J)                                                              \
    int4   e##J = make_int4(0, 0, 0, 0);                                      \
    float4 w##J = make_float4(0.f, 0.f, 0.f, 0.f);                            \
    float  b##J = 0.f;                                                        \
    bool   d##J;                                                              \
    {                                                                         \
        int k = (J) * 64 + lane;                                              \
        d##J = (k >= NUM_HID); /* out-of-range slots are born "done" */       \
        if (k < NUM_HID) {                                                    \
            e##J = ((const int4*)edge_idx)[k];                                \
            w##J = ((const float4*)w_hid)[k];                                 \
            b##J = b_hid[k];                                                  \
        }                                                                     \
    }

    LOADP(0) LOADP(1) LOADP(2) LOADP(3) LOADP(4) LOADP(5) LOADP(6) LOADP(7)

    // ---- input nodes (overlap the prefetch latency window) ----
    {
        float s = fmaf(w_in[lane], x[lane], b_in[lane]);
        vals[lane] = __builtin_amdgcn_rcpf(1.0f + __expf(-s));
    }
    if (lane < NUM_IN - 64) {
        int i = 64 + lane;
        float s = fmaf(w_in[i], x[i], b_in[i]);
        vals[i] = __builtin_amdgcn_rcpf(1.0f + __expf(-s));
    }
    // ---- hidden sentinels ----
    #pragma unroll
    for (int j = 0; j < 8; ++j) {
        int kk = j * 64 + lane;
        if (kk < NUM_HID) vals[NUM_IN + kk] = -1.0f;
    }
    __builtin_amdgcn_wave_barrier();  // compile-time ordering guard (free)

    // ---- one slot visit: skip if slot fully done; else gather 4 preds,
    //      complete node iff all preds ready (ready == sign bit clear; OR of
    //      the 4 bit patterns has sign set iff any is the -1.0f sentinel). ----
#define SLOT(J)                                                               \
    if (!__all((int)d##J)) {                                                  \
        if (!d##J) {                                                          \
            float v0 = vals[e##J.x];                                          \
            float v1 = vals[e##J.y];                                          \
            float v2 = vals[e##J.z];                                          \
            float v3 = vals[e##J.w];                                          \
            int ready = ~((__float_as_int(v0) | __float_as_int(v1) |          \
                           __float_as_int(v2) | __float_as_int(v3))) >> 31;   \
            if (ready & 1) {                                                  \
                float s = fmaf(w##J.x, v0,                                    \
                          fmaf(w##J.y, v1,                                    \
                          fmaf(w##J.z, v2,                                    \
                          fmaf(w##J.w, v3, b##J))));                          \
                vals[NUM_IN + (J) * 64 + lane] =                              \
                    __builtin_amdgcn_rcpf(1.0f + __expf(-s));                 \
                d##J = true;                                                  \
            }                                                                 \
        }                                                                     \
    }                                                                         \
    __builtin_amdgcn_wave_barrier();

    // ---- ordered sweeps; expected ~3-4, hard bound 64.
    //      unroll 1: keep code size inside the 32 KiB I-cache. ----
    bool alldone = false;
    #pragma unroll 1
    for (int sw = 0; sw < 64 && !alldone; ++sw) {
        SLOT(0) SLOT(1) SLOT(2) SLOT(3) SLOT(4) SLOT(5) SLOT(6) SLOT(7)
        alldone = __all((int)(d0 & d1 & d2 & d3 & d4 & d5 & d6 & d7));
    }

    // node 600 written by slot 7 / lane 52; same-wave program order + lgkmcnt
    // make it visible to lane 0's read here.
    if (lane == 0) out[0] = vals[TOTAL - 1];
}

extern "C" void kernel_launch(void* const* d_in, const int* in_sizes, int n_in,
                              void* d_out, int out_size, void* d_ws, size_t ws_size,
                              hipStream_t stream) {
    (void)in_sizes; (void)n_in; (void)out_size; (void)d_ws; (void)ws_size;
    const float* x     = (const float*)d_in[0];
    const float* w_in  = (const float*)d_in[1];
    const float* b_in  = (const float*)d_in[2];
    const float* w_hid = (const float*)d_in[3];
    const float* b_hid = (const float*)d_in[4];
    const int*   eidx  = (const int*)d_in[5];
    float*       out   = (float*)d_out;

    dag_kernel<<<dim3(1), dim3(64), 0, stream>>>(x, w_in, b_in, w_hid, b_hid,
                                                 eidx, out);
}